// Round 11
// baseline (600.280 us; speedup 1.0000x reference)
//
#include <hip/hip_runtime.h>

// C[b,i] = 0.125 * sum_k LI[X[b,8,3]][k] * IL[i][k]
// M=1024, N=100000, K=64.  Write-bound (409.6 MB out).
//
// v9: tile aspect flip.  R6/R8/R10 proved cached stores (109 us/pass vs NT 140).
// Residual vs 70 us roofline attacked two ways at once, micro-pattern unchanged:
//   MSLAB 256->64: LDS 9.2 KB -> occupancy cap 100% (was 50%), VGPR ~45 -> 8 waves/SIMD;
//   NSLAB 256->1024: block walks 32 consecutive 32-col chunks over the SAME 64 rows
//   -> per row 4 KB of temporally-adjacent full lines (DRAM page reuse; was one
//   isolated 128 B line per row per 256-row sweep).  IL re-read 16x, L3-resident.

#define REPS 1

typedef short short8 __attribute__((ext_vector_type(8)));
typedef float f32x4 __attribute__((ext_vector_type(4)));
typedef unsigned short ushort4v __attribute__((ext_vector_type(4)));
typedef unsigned short ushort8v __attribute__((ext_vector_type(8)));

#define KDIM  64
#define LDSS  72     // padded LDS row stride in bf16 (144 B -> 2-way bank alias only, free)
#define MSLAB 64     // A rows resident in LDS per block (9,216 B -> wave-limited occupancy)
#define NSLAB 1024   // output columns per block (32 consecutive chunks over same rows)
#define NCH   32     // columns per inner chunk (validated)

static __device__ __forceinline__ unsigned short f2bf(float f) {
    unsigned u = __float_as_uint(f);
    return (unsigned short)((u + 0x7fffu + ((u >> 16) & 1u)) >> 16);   // RNE
}

static __device__ __forceinline__ short8 cvt8(float4 v0, float4 v1) {
    union { ushort8v u; short8 s; } r;
    r.u[0] = f2bf(v0.x); r.u[1] = f2bf(v0.y); r.u[2] = f2bf(v0.z); r.u[3] = f2bf(v0.w);
    r.u[4] = f2bf(v1.x); r.u[5] = f2bf(v1.y); r.u[6] = f2bf(v1.z); r.u[7] = f2bf(v1.w);
    return r.s;
}

// ---- Phase 1: A[b][k] = bf16(LI[X[b,8,3]][k]) into ws. ----
__global__ __launch_bounds__(256)
void fpmc_gather(const int* __restrict__ X, const float* __restrict__ LI,
                 unsigned short* __restrict__ ws, int M) {
    const int t = threadIdx.x;
    const int r = blockIdx.x * 16 + (t >> 4);
    if (r >= M) return;
    const int c = (t & 15) * 4;
    const int idx = X[r * 40 + 35];                    // X[b, 8, 3]
    const float4 v = *(const float4*)(LI + (size_t)idx * KDIM + c);
    ushort4v p;
    p.x = f2bf(v.x); p.y = f2bf(v.y); p.z = f2bf(v.z); p.w = f2bf(v.w);
    *(ushort4v*)(ws + (size_t)r * KDIM + c) = p;
}

// ---- Phase 2: stream IL, MFMA vs LDS-resident 64-row A-slab, cached stores. ----
template<bool USE_WS>
__global__ __launch_bounds__(256, 8)
void fpmc_gemm2(const int* __restrict__ X, const float* __restrict__ IL,
                const float* __restrict__ LI, const unsigned short* __restrict__ Aws,
                float* __restrict__ out, int M, int N) {
    __shared__ __align__(16) unsigned short As[MSLAB * LDSS];   // 9,216 B

    const int t  = threadIdx.x;
    const int m0 = blockIdx.y * MSLAB;
    const int i0 = blockIdx.x * NSLAB;

    if (USE_WS) {
        // coalesced copy ws -> LDS: 512 short8 chunks, 2 per thread
        #pragma unroll
        for (int it = 0; it < 2; ++it) {
            const int chunk = it * 256 + t;
            const int r = chunk >> 3;
            const int c = (chunk & 7) * 8;
            ushort8v v = *(const ushort8v*)(Aws + (size_t)(m0 + r) * KDIM + c);
            *(ushort8v*)&As[r * LDSS + c] = v;
        }
    } else {
        const int rb = t >> 4;
        const int c  = (t & 15) * 4;
        #pragma unroll
        for (int it = 0; it < MSLAB / 16; ++it) {
            const int r = it * 16 + rb;
            const int idx = X[(m0 + r) * 40 + 35];
            const float4 v = *(const float4*)(LI + (size_t)idx * KDIM + c);
            ushort4v p;
            p.x = f2bf(v.x); p.y = f2bf(v.y); p.z = f2bf(v.z); p.w = f2bf(v.w);
            *(ushort4v*)&As[r * LDSS + c] = p;
        }
    }
    __syncthreads();

    // wave w owns m-rows [w*16, w*16+16); walks 32 consecutive 32-col chunks
    const int w    = t >> 6;
    const int l    = t & 63;
    const int lr   = l & 15;
    const int quad = l >> 4;
    const int mwav = w * 16;
    const float scale = 0.125f;

    // hoist A fragments (nc-invariant): a[ks], 8 VGPR
    short8 a[2];
    #pragma unroll
    for (int ks = 0; ks < 2; ++ks)
        a[ks] = *(const short8*)&As[(mwav + lr) * LDSS + ks * 32 + quad * 8];

    #pragma unroll 1
    for (int rep = 0; rep < REPS; ++rep) {
        #pragma unroll 1
        for (int nc = 0; nc < NSLAB / NCH; ++nc) {
            const int n0c = i0 + nc * NCH;

            f32x4 acc[2];
            acc[0] = (f32x4){0.f, 0.f, 0.f, 0.f};
            acc[1] = (f32x4){0.f, 0.f, 0.f, 0.f};

            #pragma unroll
            for (int ks = 0; ks < 2; ++ks) {
                short8 b[2];
                #pragma unroll
                for (int nt = 0; nt < 2; ++nt) {
                    int n = n0c + nt * 16 + lr;
                    if (n > N - 1) n = N - 1;          // clamp; stores guarded below
                    const float* p = IL + (size_t)n * KDIM + ks * 32 + quad * 8;
                    b[nt] = cvt8(*(const float4*)p, *(const float4*)(p + 4));
                }
                #pragma unroll
                for (int nt = 0; nt < 2; ++nt)
                    acc[nt] = __builtin_amdgcn_mfma_f32_16x16x32_bf16(
                        b[nt], a[ks], acc[nt], 0, 0, 0);
            }

            // cached stores: nt=0/1 back-to-back assemble full 128 B lines;
            // consecutive nc revisit the same rows at adjacent n -> page reuse.
            const int m = m0 + mwav + lr;
            float* orow = out + (size_t)m * N;
            #pragma unroll
            for (int nt = 0; nt < 2; ++nt) {
                const int n = n0c + nt * 16 + quad * 4;
                if (n < N)                              // N%4==0 -> whole-f32x4 guard
                    *(f32x4*)(orow + n) = acc[nt] * scale;
            }
        }
        asm volatile("" ::: "memory");
    }
}

extern "C" void kernel_launch(void* const* d_in, const int* in_sizes, int n_in,
                              void* d_out, int out_size, void* d_ws, size_t ws_size,
                              hipStream_t stream) {
    const int*   X  = (const int*)d_in[0];
    const float* IL = (const float*)d_in[1];
    const float* LI = (const float*)d_in[2];
    float* out = (float*)d_out;

    const int M = in_sizes[0] / 40;      // 1024
    const int N = in_sizes[1] / KDIM;    // 100000

    unsigned short* Aws = (unsigned short*)d_ws;
    const size_t need = (size_t)M * KDIM * sizeof(unsigned short);   // 128 KB

    dim3 grid((N + NSLAB - 1) / NSLAB, (M + MSLAB - 1) / MSLAB);     // (98, 16)
    if (d_ws != nullptr && ws_size >= need) {
        fpmc_gather<<<dim3((M + 15) / 16), dim3(256), 0, stream>>>(X, LI, Aws, M);
        fpmc_gemm2<true><<<grid, dim3(256), 0, stream>>>(X, IL, LI, Aws, out, M, N);
    } else {
        fpmc_gemm2<false><<<grid, dim3(256), 0, stream>>>(X, IL, LI, Aws, out, M, N);
    }
}

// Round 12
// 499.787 us; speedup vs baseline: 1.2011x; 1.2011x over previous
//
#include <hip/hip_runtime.h>

// C[b,i] = 0.125 * sum_k LI[X[b,8,3]][k] * IL[i][k]
// M=1024, N=100000, K=64.  Write-bound (409.6 MB out).
//
// v10: residency probe.  Validated base (v8/R10, 468 us): 256x256 tile, NCH=32,
// cached f32x4 stores, one-time bf16 A-gather, IL ratio 0.5.  ONE change:
// 256->512 threads (8 waves x 32 rows, mt=2).  Per-thread regs SHRINK
// (acc 16, A-frags 16 hoisted, b 8 -> ~55) so the 4 LDS-limited blocks/CU now
// hold 32 waves/CU (100% cap, was 16/32=50%, achieved 31% in R6) -> more
// outstanding mem ops -> higher achieved write BW.  IL traffic unchanged.
// R11 lesson encoded: wave B-bytes/out-bytes stays 0.5 (v9's 2.0 cost 2.3x).

typedef short short8 __attribute__((ext_vector_type(8)));
typedef float f32x4 __attribute__((ext_vector_type(4)));
typedef unsigned short ushort4v __attribute__((ext_vector_type(4)));
typedef unsigned short ushort8v __attribute__((ext_vector_type(8)));

#define KDIM  64
#define LDSS  72     // padded LDS row stride in bf16 (144 B -> 2-way bank alias only, free)
#define MSLAB 256    // A rows resident in LDS per block
#define NSLAB 256    // output columns per block
#define NCH   32     // columns per inner chunk (validated)

static __device__ __forceinline__ unsigned short f2bf(float f) {
    unsigned u = __float_as_uint(f);
    return (unsigned short)((u + 0x7fffu + ((u >> 16) & 1u)) >> 16);   // RNE
}

static __device__ __forceinline__ short8 cvt8(float4 v0, float4 v1) {
    union { ushort8v u; short8 s; } r;
    r.u[0] = f2bf(v0.x); r.u[1] = f2bf(v0.y); r.u[2] = f2bf(v0.z); r.u[3] = f2bf(v0.w);
    r.u[4] = f2bf(v1.x); r.u[5] = f2bf(v1.y); r.u[6] = f2bf(v1.z); r.u[7] = f2bf(v1.w);
    return r.s;
}

// ---- Phase 1: A[b][k] = bf16(LI[X[b,8,3]][k]) into ws. ----
__global__ __launch_bounds__(256)
void fpmc_gather(const int* __restrict__ X, const float* __restrict__ LI,
                 unsigned short* __restrict__ ws, int M) {
    const int t = threadIdx.x;
    const int r = blockIdx.x * 16 + (t >> 4);
    if (r >= M) return;
    const int c = (t & 15) * 4;
    const int idx = X[r * 40 + 35];                    // X[b, 8, 3]
    const float4 v = *(const float4*)(LI + (size_t)idx * KDIM + c);
    ushort4v p;
    p.x = f2bf(v.x); p.y = f2bf(v.y); p.z = f2bf(v.z); p.w = f2bf(v.w);
    *(ushort4v*)(ws + (size_t)r * KDIM + c) = p;
}

// ---- Phase 2: 8-wave blocks, stream IL, MFMA vs LDS A-slab, cached stores. ----
template<bool USE_WS>
__global__ __launch_bounds__(512)
void fpmc_gemm2(const int* __restrict__ X, const float* __restrict__ IL,
                const float* __restrict__ LI, const unsigned short* __restrict__ Aws,
                float* __restrict__ out, int M, int N) {
    __shared__ __align__(16) unsigned short As[MSLAB * LDSS];   // 36,864 B -> 4 blocks/CU

    const int t  = threadIdx.x;
    const int m0 = blockIdx.y * MSLAB;
    const int i0 = blockIdx.x * NSLAB;

    if (USE_WS) {
        // coalesced copy ws -> LDS: 2048 short8 chunks, 4 per thread
        #pragma unroll
        for (int it = 0; it < 4; ++it) {
            const int chunk = it * 512 + t;
            const int r = chunk >> 3;
            const int c = (chunk & 7) * 8;
            ushort8v v = *(const ushort8v*)(Aws + (size_t)(m0 + r) * KDIM + c);
            *(ushort8v*)&As[r * LDSS + c] = v;
        }
    } else {
        const int rb = t >> 5;          // 0..15
        const int c  = (t & 31) * 2;    // 0..62 step 2
        #pragma unroll
        for (int it = 0; it < MSLAB / 16; ++it) {
            const int r = it * 16 + rb;
            const int idx = X[(m0 + r) * 40 + 35];
            const float2 v = *(const float2*)(LI + (size_t)idx * KDIM + c);
            unsigned short p0 = f2bf(v.x), p1 = f2bf(v.y);
            As[r * LDSS + c]     = p0;
            As[r * LDSS + c + 1] = p1;
        }
    }
    __syncthreads();

    // wave w owns m-rows [w*32, w*32+32); mt in {0,1}
    const int w    = t >> 6;         // 0..7
    const int l    = t & 63;
    const int lr   = l & 15;
    const int quad = l >> 4;
    const int mwav = w * 32;
    const float scale = 0.125f;

    // hoist A fragments (nc-invariant): a[ks][mt], 16 VGPR; LDS read once
    short8 a[2][2];
    #pragma unroll
    for (int ks = 0; ks < 2; ++ks)
        #pragma unroll
        for (int mt = 0; mt < 2; ++mt)
            a[ks][mt] = *(const short8*)&As[(mwav + mt * 16 + lr) * LDSS + ks * 32 + quad * 8];

    #pragma unroll 1
    for (int nc = 0; nc < NSLAB / NCH; ++nc) {
        const int n0c = i0 + nc * NCH;

        f32x4 acc[2][2];
        #pragma unroll
        for (int mt = 0; mt < 2; ++mt)
            #pragma unroll
            for (int nt = 0; nt < 2; ++nt)
                acc[mt][nt] = (f32x4){0.f, 0.f, 0.f, 0.f};

        #pragma unroll
        for (int ks = 0; ks < 2; ++ks) {
            short8 b[2];
            #pragma unroll
            for (int nt = 0; nt < 2; ++nt) {
                int n = n0c + nt * 16 + lr;
                if (n > N - 1) n = N - 1;              // clamp; stores guarded below
                const float* p = IL + (size_t)n * KDIM + ks * 32 + quad * 8;
                b[nt] = cvt8(*(const float4*)p, *(const float4*)(p + 4));
            }
            #pragma unroll
            for (int mt = 0; mt < 2; ++mt)
                #pragma unroll
                for (int nt = 0; nt < 2; ++nt)
                    acc[mt][nt] = __builtin_amdgcn_mfma_f32_16x16x32_bf16(
                        b[nt], a[ks][mt], acc[mt][nt], 0, 0, 0);
        }

        // CACHED stores: nt=0/1 back-to-back assemble full 128 B L2 lines.
        #pragma unroll
        for (int mt = 0; mt < 2; ++mt) {
            const int m = m0 + mwav + mt * 16 + lr;
            float* orow = out + (size_t)m * N;
            #pragma unroll
            for (int nt = 0; nt < 2; ++nt) {
                const int n = n0c + nt * 16 + quad * 4;
                if (n < N)                              // N%4==0 -> whole-f32x4 guard
                    *(f32x4*)(orow + n) = acc[mt][nt] * scale;
            }
        }
    }
}

extern "C" void kernel_launch(void* const* d_in, const int* in_sizes, int n_in,
                              void* d_out, int out_size, void* d_ws, size_t ws_size,
                              hipStream_t stream) {
    const int*   X  = (const int*)d_in[0];
    const float* IL = (const float*)d_in[1];
    const float* LI = (const float*)d_in[2];
    float* out = (float*)d_out;

    const int M = in_sizes[0] / 40;      // 1024
    const int N = in_sizes[1] / KDIM;    // 100000

    unsigned short* Aws = (unsigned short*)d_ws;
    const size_t need = (size_t)M * KDIM * sizeof(unsigned short);   // 128 KB

    dim3 grid((N + NSLAB - 1) / NSLAB, (M + MSLAB - 1) / MSLAB);     // (391, 4)
    if (d_ws != nullptr && ws_size >= need) {
        fpmc_gather<<<dim3((M + 15) / 16), dim3(256), 0, stream>>>(X, LI, Aws, M);
        fpmc_gemm2<true><<<grid, dim3(512), 0, stream>>>(X, IL, LI, Aws, out, M, N);
    } else {
        fpmc_gemm2<false><<<grid, dim3(512), 0, stream>>>(X, IL, LI, Aws, out, M, N);
    }
}

// Round 13
// 473.464 us; speedup vs baseline: 1.2678x; 1.0556x over previous
//
#include <hip/hip_runtime.h>

// C[b,i] = 0.125 * sum_k LI[X[b,8,3]][k] * IL[i][k]
// M=1024, N=100000, K=64.  Write-bound (409.6 MB out).
//
// v8-final (= R10's validated session best, 468.5 us; reverted after R9/R11/R12
// probes all regressed).  Mechanisms locked in by counter evidence:
//  - cached f32x4 stores, NOT nontemporal: R6 counters showed NT = 1.36x write
//    amplification + DRAM-latency completion (140 us/pass); cached = 109 us/pass
//    (R8 A/B).  Back-to-back nt=0/1 stores assemble full 128 B L2 lines.
//  - one-time bf16 A-gather via X into ws (phase 1), 256-row A-slab in LDS.
//  - IL streamed global->reg with in-reg bf16 convert (no B staging).
//  - 256x256 tile, NCH=32: IL-traffic/out-traffic = 0.5 (v9's 2.0 cost 2.3x);
//    NCH=64 (R9) and 8-wave blocks (R12) both regressed -> kept at R10 config.
// Residual vs 70 us pure-BW roofline attributed to mixed R/W stream turnaround
// + 128 B-granule write scatter across 1024 concurrent row-streams (~80% of
// realistic mixed ceiling); three counter-motivated attacks falsified.

#define REPS 1

typedef short short8 __attribute__((ext_vector_type(8)));
typedef float f32x4 __attribute__((ext_vector_type(4)));
typedef unsigned short ushort4v __attribute__((ext_vector_type(4)));
typedef unsigned short ushort8v __attribute__((ext_vector_type(8)));

#define KDIM  64
#define LDSS  72     // padded LDS row stride in bf16 (144 B -> 2-way bank alias only, free)
#define MSLAB 256    // A rows resident in LDS per block
#define NSLAB 256    // output columns per block
#define NCH   32     // columns per inner chunk

static __device__ __forceinline__ unsigned short f2bf(float f) {
    unsigned u = __float_as_uint(f);
    return (unsigned short)((u + 0x7fffu + ((u >> 16) & 1u)) >> 16);   // RNE
}

static __device__ __forceinline__ short8 cvt8(float4 v0, float4 v1) {
    union { ushort8v u; short8 s; } r;
    r.u[0] = f2bf(v0.x); r.u[1] = f2bf(v0.y); r.u[2] = f2bf(v0.z); r.u[3] = f2bf(v0.w);
    r.u[4] = f2bf(v1.x); r.u[5] = f2bf(v1.y); r.u[6] = f2bf(v1.z); r.u[7] = f2bf(v1.w);
    return r.s;
}

// ---- Phase 1: A[b][k] = bf16(LI[X[b,8,3]][k]) into ws. ----
__global__ __launch_bounds__(256)
void fpmc_gather(const int* __restrict__ X, const float* __restrict__ LI,
                 unsigned short* __restrict__ ws, int M) {
    const int t = threadIdx.x;
    const int r = blockIdx.x * 16 + (t >> 4);
    if (r >= M) return;
    const int c = (t & 15) * 4;
    const int idx = X[r * 40 + 35];                    // X[b, 8, 3]
    const float4 v = *(const float4*)(LI + (size_t)idx * KDIM + c);
    ushort4v p;
    p.x = f2bf(v.x); p.y = f2bf(v.y); p.z = f2bf(v.z); p.w = f2bf(v.w);
    *(ushort4v*)(ws + (size_t)r * KDIM + c) = p;
}

// ---- Phase 2: stream IL, MFMA vs LDS-resident A-slab, CACHED stores. ----
template<bool USE_WS>
__global__ __launch_bounds__(256, 4)
void fpmc_gemm2(const int* __restrict__ X, const float* __restrict__ IL,
                const float* __restrict__ LI, const unsigned short* __restrict__ Aws,
                float* __restrict__ out, int M, int N) {
    __shared__ __align__(16) unsigned short As[MSLAB * LDSS];   // 36,864 B -> 4 blocks/CU

    const int t  = threadIdx.x;
    const int m0 = blockIdx.y * MSLAB;
    const int i0 = blockIdx.x * NSLAB;

    if (USE_WS) {
        #pragma unroll
        for (int it = 0; it < 8; ++it) {
            const int chunk = it * 256 + t;
            const int r = chunk >> 3;
            const int c = (chunk & 7) * 8;
            ushort8v v = *(const ushort8v*)(Aws + (size_t)(m0 + r) * KDIM + c);
            *(ushort8v*)&As[r * LDSS + c] = v;
        }
    } else {
        const int rb = t >> 4;
        const int c  = (t & 15) * 4;
        #pragma unroll
        for (int it = 0; it < MSLAB / 16; ++it) {
            const int r = it * 16 + rb;
            const int idx = X[(m0 + r) * 40 + 35];
            const float4 v = *(const float4*)(LI + (size_t)idx * KDIM + c);
            ushort4v p;
            p.x = f2bf(v.x); p.y = f2bf(v.y); p.z = f2bf(v.z); p.w = f2bf(v.w);
            *(ushort4v*)&As[r * LDSS + c] = p;
        }
    }
    __syncthreads();

    const int w    = t >> 6;
    const int l    = t & 63;
    const int lr   = l & 15;
    const int quad = l >> 4;
    const int mwav = w * 64;
    const float scale = 0.125f;

    #pragma unroll 1
    for (int rep = 0; rep < REPS; ++rep) {
        #pragma unroll 1
        for (int nc = 0; nc < NSLAB / NCH; ++nc) {
            const int n0c = i0 + nc * NCH;

            f32x4 acc[4][2];
            #pragma unroll
            for (int mt = 0; mt < 4; ++mt)
                #pragma unroll
                for (int nt = 0; nt < 2; ++nt)
                    acc[mt][nt] = (f32x4){0.f, 0.f, 0.f, 0.f};

            #pragma unroll
            for (int ks = 0; ks < 2; ++ks) {
                short8 b[2];
                #pragma unroll
                for (int nt = 0; nt < 2; ++nt) {
                    int n = n0c + nt * 16 + lr;
                    if (n > N - 1) n = N - 1;          // clamp; stores guarded below
                    const float* p = IL + (size_t)n * KDIM + ks * 32 + quad * 8;
                    b[nt] = cvt8(*(const float4*)p, *(const float4*)(p + 4));
                }
                short8 a[4];
                #pragma unroll
                for (int mt = 0; mt < 4; ++mt)
                    a[mt] = *(const short8*)&As[(mwav + mt * 16 + lr) * LDSS + ks * 32 + quad * 8];
                #pragma unroll
                for (int mt = 0; mt < 4; ++mt)
                    #pragma unroll
                    for (int nt = 0; nt < 2; ++nt)
                        acc[mt][nt] = __builtin_amdgcn_mfma_f32_16x16x32_bf16(
                            b[nt], a[mt], acc[mt][nt], 0, 0, 0);
            }

            // CACHED stores: nt=0/1 back-to-back from the same wave assemble
            // each 128B line in L2; full-line eviction, L2-latency completion.
            #pragma unroll
            for (int mt = 0; mt < 4; ++mt) {
                const int m = m0 + mwav + mt * 16 + lr;
                float* orow = out + (size_t)m * N;
                #pragma unroll
                for (int nt = 0; nt < 2; ++nt) {
                    const int n = n0c + nt * 16 + quad * 4;
                    if (n < N)                          // N%4==0 -> whole-f32x4 guard
                        *(f32x4*)(orow + n) = acc[mt][nt] * scale;
                }
            }
        }
        asm volatile("" ::: "memory");
    }
}

extern "C" void kernel_launch(void* const* d_in, const int* in_sizes, int n_in,
                              void* d_out, int out_size, void* d_ws, size_t ws_size,
                              hipStream_t stream) {
    const int*   X  = (const int*)d_in[0];
    const float* IL = (const float*)d_in[1];
    const float* LI = (const float*)d_in[2];
    float* out = (float*)d_out;

    const int M = in_sizes[0] / 40;      // 1024
    const int N = in_sizes[1] / KDIM;    // 100000

    unsigned short* Aws = (unsigned short*)d_ws;
    const size_t need = (size_t)M * KDIM * sizeof(unsigned short);   // 128 KB

    dim3 grid((N + NSLAB - 1) / NSLAB, (M + MSLAB - 1) / MSLAB);
    if (d_ws != nullptr && ws_size >= need) {
        fpmc_gather<<<dim3((M + 15) / 16), dim3(256), 0, stream>>>(X, LI, Aws, M);
        fpmc_gemm2<true><<<grid, dim3(256), 0, stream>>>(X, IL, LI, Aws, out, M, N);
    } else {
        fpmc_gemm2<false><<<grid, dim3(256), 0, stream>>>(X, IL, LI, Aws, out, M, N);
    }
}